// Round 6
// baseline (190.630 us; speedup 1.0000x reference)
//
#include <hip/hip_runtime.h>
#include <cstdint>
#include <cstddef>

// Problem constants
#define NUM_CODES 1024
#define DIM       256
#define NROWS     65536          // BATCH(8192) * NODE(8)
#define BM        64             // rows per block
#define LDS_STRIDE 272           // 256 fp8 bytes + 16 pad (8B aligned, 2-way banks)
#define OUT0_ELEMS 16777216      // 8192*8*256

typedef float v4f  __attribute__((ext_vector_type(4)));

// v_cvt_pk_fp8_f32: word-select (4th arg) must be a compile-time constant.
__device__ inline unsigned cvt_pk_fp8_lo(float lo, float hi) {
  return (unsigned)__builtin_amdgcn_cvt_pk_fp8_f32(lo, hi, 0, false);
}
__device__ inline unsigned cvt_pk_fp8_hi(float lo, float hi, unsigned old) {
  return (unsigned)__builtin_amdgcn_cvt_pk_fp8_f32(lo, hi, (int)old, true);
}

// One block per code k (1024 blocks, 256 threads = one per d).
// B stored as e4m3 of (512*e): raw e in (-1e-3,1e-3) is DENORMAL in e4m3
// (granularity 2^-9) -- scaling by 512 puts it in the normal range.
// c0[k] = 256 - 256*||e||^2 : MFMA C-init, so after the K-loop
// acc = 256 + 512*(dot - ||e||^2/2). |512*dot| <= ||x||*||512e|| <= 20*8.7 = 174
// => acc in [82, 430] > 0 (Cauchy-Schwarz, worst case): u32 compare == f32 compare.
__global__ __launch_bounds__(256) void vq_prep(const float* __restrict__ emb,
                                               unsigned char* __restrict__ eprep,
                                               float* __restrict__ c0,
                                               float* __restrict__ loss_slot) {
  const int k = blockIdx.x;
  const int d = threadIdx.x;
  float v = emb[k * DIM + d];

  float sq = v * v;
  #pragma unroll
  for (int off = 32; off; off >>= 1) sq += __shfl_down(sq, off);
  __shared__ float red[4];
  const int lane = threadIdx.x & 63, wv = threadIdx.x >> 6;
  if (lane == 0) red[wv] = sq;
  __syncthreads();
  if (threadIdx.x == 0) c0[k] = 256.0f - 256.0f * (red[0] + red[1] + red[2] + red[3]);
  if (blockIdx.x == 0 && threadIdx.x == 0) *loss_slot = 0.0f;

  // B-fragment layout for mfma_f32_16x16x32_fp8_fp8 (same indexing as bf16,
  // 1 byte/elem): lane l holds B[kdim=(l>>4)*8+j][n=l&15]; tile = 16 codes x 32 d
  const int c16 = k >> 4;
  const int kk = d >> 5;
  const int quad = (d >> 3) & 3;
  const int j = d & 7;
  const int l = quad * 16 + (k & 15);
  const unsigned b8 = cvt_pk_fp8_lo(512.0f * v, 512.0f * v) & 0xFFu;
  eprep[(((c16 * 8 + kk) * 64) + l) * 8 + j] = (unsigned char)b8;
}

// 1024 blocks x 256 threads (4 waves = 4 code-groups, each covering all 64 rows).
// R1/R2 law: ANY launch-bounds demand below the working set spills -> (256,2) only.
// R3: nontemporal out-stores defeat L3 write absorption -> plain stores.
// R5: fp8 e4m3 scoring (X unscaled, E x512). Sum-regime accounting at 52.8us:
// HBM 16.7 + LDS 10.2 + MFMA 13 + VALU 8 + L2 7.4 ~= 56 ~= measured -> pipes
// barely overlap; removing work from any pipe pays ~1:1.
// R6: A-fragments are ct-invariant -> read them ONCE into 64 VGPRs (one
// 32x ds_read_b64 pass) instead of re-reading LDS every code-tile (8x).
// Also hoist all 16 c0 values into regs before the barrier (removes the
// serialized global load gating each ct's first MFMA).
__global__ __launch_bounds__(256, 2) void vq_main(const float* __restrict__ lat,
                                                  const float* __restrict__ emb,
                                                  const unsigned char* __restrict__ eprep,
                                                  const float* __restrict__ c0arr,
                                                  float* __restrict__ out,
                                                  float* __restrict__ loss_slot) {
  __shared__ __align__(16) unsigned char xlds[BM * LDS_STRIDE];
  __shared__ unsigned smax[BM];
  __shared__ float lred[4];

  const int tid = threadIdx.x;
  const int lane = tid & 63;
  const int cg = tid >> 6;           // wave 0..3 = code-group
  const int lane15 = lane & 15;
  const int quad = lane >> 4;
  const size_t rowbase_g = (size_t)blockIdx.x * BM;

  // ---- stage X tile: fp32 global -> fp8 LDS; accumulate ||x||^2 in fp32 ----
  if (tid < BM) smax[tid] = 0u;
  float x2 = 0.0f;
  const v4f* latv = (const v4f*)(lat + rowbase_g * DIM);
  #pragma unroll
  for (int i = 0; i < 16; ++i) {
    int g = i * 256 + tid;           // 4096 float4 per tile
    int row = g >> 6;                // 64 float4 per row
    int c4 = g & 63;
    v4f v = latv[g];
    x2 = fmaf(v.x, v.x, x2); x2 = fmaf(v.y, v.y, x2);
    x2 = fmaf(v.z, v.z, x2); x2 = fmaf(v.w, v.w, x2);
    unsigned w = cvt_pk_fp8_lo(v.x, v.y);
    w = cvt_pk_fp8_hi(v.z, v.w, w);
    *(unsigned*)(&xlds[row * LDS_STRIDE + c4 * 4]) = w;
  }

  // hoist per-ct column constants while the staging stores drain
  float c0v[8][2];
  #pragma unroll
  for (int ct = 0; ct < 8; ++ct) {
    c0v[ct][0] = c0arr[ct * 128 + cg * 32 + lane15];
    c0v[ct][1] = c0arr[ct * 128 + cg * 32 + 16 + lane15];
  }
  __syncthreads();

  // ---- read the wave's ct-invariant A-fragments ONCE into registers ----
  long afr[4][8];                    // 64 VGPRs: 4 mf x 8 kk x 8 bytes
  #pragma unroll
  for (int mf = 0; mf < 4; ++mf)
    #pragma unroll
    for (int kk = 0; kk < 8; ++kk)
      afr[mf][kk] = *(const long*)(&xlds[(mf * 16 + lane15) * LDS_STRIDE + kk * 32 + quad * 8]);

  // ---- MFMA score tiles + running packed argmax (no LDS in this loop) ----
  unsigned kmax[16];
  #pragma unroll
  for (int s = 0; s < 16; ++s) kmax[s] = 0u;

  const long* __restrict__ bptr = (const long*)eprep;

  #pragma unroll 1
  for (int ct = 0; ct < 8; ++ct) {           // 8 code tiles of 128
    const int cb = ct * 128 + cg * 32;       // wave's code base (32 codes)
    const int c16b = cb >> 4;

    v4f acc[4][2];
    #pragma unroll
    for (int mf = 0; mf < 4; ++mf) {
      const float c0a = c0v[ct][0], c0b = c0v[ct][1];
      acc[mf][0] = (v4f){c0a, c0a, c0a, c0a};
      acc[mf][1] = (v4f){c0b, c0b, c0b, c0b};
    }

    #pragma unroll
    for (int kk = 0; kk < 8; ++kk) {         // D=256 in steps of 32
      long b[2];
      #pragma unroll
      for (int nf = 0; nf < 2; ++nf)
        b[nf] = bptr[((c16b + nf) * 8 + kk) * 64 + lane];
      #pragma unroll
      for (int mf = 0; mf < 4; ++mf)
        #pragma unroll
        for (int nf = 0; nf < 2; ++nf)
          acc[mf][nf] = __builtin_amdgcn_mfma_f32_16x16x32_fp8_fp8(afr[mf][kk], b[nf], acc[mf][nf], 0, 0, 0);
    }

    // pack: key = (acc_bits & ~1023) | (1023-code); larger acc = smaller dist.
    const unsigned cc0 = (unsigned)(1023 - (cb + lane15));
    const unsigned cc1 = cc0 - 16u;
    #pragma unroll
    for (int nf = 0; nf < 2; ++nf) {
      const unsigned cc = nf ? cc1 : cc0;
      #pragma unroll
      for (int mf = 0; mf < 4; ++mf)
        #pragma unroll
        for (int i = 0; i < 4; ++i) {
          const unsigned key =
              (__builtin_bit_cast(unsigned, acc[mf][nf][i]) & 0xFFFFFC00u) | cc;
          const int s = mf * 4 + i;
          kmax[s] = key > kmax[s] ? key : kmax[s];
        }
    }
  }

  // ---- reduce across the 16 lanes sharing a quad (single u32 max) ----
  #pragma unroll
  for (int s = 0; s < 16; ++s) {
    #pragma unroll
    for (int mask = 1; mask <= 8; mask <<= 1) {
      const unsigned o = __shfl_xor(kmax[s], mask);
      kmax[s] = o > kmax[s] ? o : kmax[s];
    }
  }
  // cross-wave combine: 4 lanes/wave x 16 rows each via LDS atomicMax
  if (lane15 == 0) {
    #pragma unroll
    for (int mf = 0; mf < 4; ++mf)
      #pragma unroll
      for (int i = 0; i < 4; ++i)
        atomicMax(&smax[mf * 16 + quad * 4 + i], kmax[mf * 4 + i]);
  }
  __syncthreads();

  // ---- epilogue: gather + store only. wave cg owns rows cg*16..cg*16+15 ----
  float* outg = out + rowbase_g * DIM;
  #pragma unroll 4
  for (int j = 0; j < 16; ++j) {
    const int r = cg * 16 + j;
    const int code = (int)((~smax[r]) & 1023u);
    const v4f ev = *(const v4f*)(emb + code * DIM + lane * 4);
    *(v4f*)(outg + (size_t)r * DIM + lane * 4) = ev;
  }

  // ---- loss: dist_row = ||x||^2 - 2*(acc_win-256)/512; one atomic per block ----
  #pragma unroll
  for (int off = 32; off; off >>= 1) x2 += __shfl_down(x2, off);
  if (lane == 0) lred[cg] = x2;
  float ssum = 0.0f;
  if (cg == 0) {            // wave 0: decode the 64 winners' scaled scores
    ssum = __builtin_bit_cast(float, smax[lane] & 0xFFFFFC00u) - 256.0f;
    #pragma unroll
    for (int off = 32; off; off >>= 1) ssum += __shfl_down(ssum, off);
  }
  __syncthreads();
  if (tid == 0) {
    const float xs = lred[0] + lred[1] + lred[2] + lred[3];
    atomicAdd(loss_slot, (xs - ssum * (2.0f / 512.0f)) * (1.25f / 16777216.0f));
  }
}

extern "C" void kernel_launch(void* const* d_in, const int* in_sizes, int n_in,
                              void* d_out, int out_size, void* d_ws, size_t ws_size,
                              hipStream_t stream) {
  const float* lat = (const float*)d_in[0];   // [8192, 2048] fp32
  const float* emb = (const float*)d_in[1];   // [1024, 256] fp32
  float* out = (float*)d_out;                 // [16777216] quantized_st + [1] vq_loss
  unsigned char* eprep = (unsigned char*)d_ws;                      // 256 KiB
  float* c0 = (float*)((char*)d_ws + NUM_CODES * DIM);
  float* loss_slot = out + (size_t)OUT0_ELEMS;

  vq_prep<<<NUM_CODES, 256, 0, stream>>>(emb, eprep, c0, loss_slot);
  vq_main<<<NROWS / BM, 256, 0, stream>>>(lat, emb, eprep, c0, out, loss_slot);
}

// Round 7
// 136.739 us; speedup vs baseline: 1.3941x; 1.3941x over previous
//
#include <hip/hip_runtime.h>
#include <cstdint>
#include <cstddef>

// Problem constants
#define NUM_CODES 1024
#define DIM       256
#define NROWS     65536          // BATCH(8192) * NODE(8)
#define BM        64             // rows per block
#define LDS_STRIDE 272           // 256 fp8 bytes + 16 pad (8B aligned, 2-way banks)
#define OUT0_ELEMS 16777216      // 8192*8*256

typedef float v4f  __attribute__((ext_vector_type(4)));

// v_cvt_pk_fp8_f32: word-select (4th arg) must be a compile-time constant.
__device__ inline unsigned cvt_pk_fp8_lo(float lo, float hi) {
  return (unsigned)__builtin_amdgcn_cvt_pk_fp8_f32(lo, hi, 0, false);
}
__device__ inline unsigned cvt_pk_fp8_hi(float lo, float hi, unsigned old) {
  return (unsigned)__builtin_amdgcn_cvt_pk_fp8_f32(lo, hi, (int)old, true);
}

// One block per code k (1024 blocks, 256 threads = one per d).
// B stored as e4m3 of (512*e): raw e in (-1e-3,1e-3) is DENORMAL in e4m3
// (granularity 2^-9) -- scaling by 512 puts it in the normal range.
// c0[k] = 256 - 256*||e||^2 : MFMA C-init, so after the K-loop
// acc = 256 + 512*(dot - ||e||^2/2). |512*dot| <= ||x||*||512e|| <= 20*8.7 = 174
// => acc in [82, 430] > 0 (Cauchy-Schwarz, worst case): u32 compare == f32 compare.
__global__ __launch_bounds__(256) void vq_prep(const float* __restrict__ emb,
                                               unsigned char* __restrict__ eprep,
                                               float* __restrict__ c0,
                                               float* __restrict__ loss_slot) {
  const int k = blockIdx.x;
  const int d = threadIdx.x;
  float v = emb[k * DIM + d];

  float sq = v * v;
  #pragma unroll
  for (int off = 32; off; off >>= 1) sq += __shfl_down(sq, off);
  __shared__ float red[4];
  const int lane = threadIdx.x & 63, wv = threadIdx.x >> 6;
  if (lane == 0) red[wv] = sq;
  __syncthreads();
  if (threadIdx.x == 0) c0[k] = 256.0f - 256.0f * (red[0] + red[1] + red[2] + red[3]);
  if (blockIdx.x == 0 && threadIdx.x == 0) *loss_slot = 0.0f;

  // B-fragment layout for mfma_f32_16x16x32_fp8_fp8 (same indexing as bf16,
  // 1 byte/elem): lane l holds B[kdim=(l>>4)*8+j][n=l&15]; tile = 16 codes x 32 d
  const int c16 = k >> 4;
  const int kk = d >> 5;
  const int quad = (d >> 3) & 3;
  const int j = d & 7;
  const int l = quad * 16 + (k & 15);
  const unsigned b8 = cvt_pk_fp8_lo(512.0f * v, 512.0f * v) & 0xFFu;
  eprep[(((c16 * 8 + kk) * 64) + l) * 8 + j] = (unsigned char)b8;
}

// 1024 blocks x 512 threads (8 waves, nf=1: each wave owns 16 codes per ct).
// R1/R2 law: no launch-bounds demand below the working set -> (512,2) = 256-reg cap.
// R3: plain out-stores (nontemporal defeats L3 write absorption).
// R5: fp8 e4m3 scoring. R6 lesson: do NOT hand-roll A-reuse or pin the ct loop --
// the compiler fully unrolls it and CSEs the ct-invariant LDS A-reads into regs
// (that IS R5's 112-VGPR allocation); pragma unroll 1 forced both undone (2x slower).
// R7: generation pipelining. 8 waves x ~115 regs admit only 1-2 of the 4
// blocks/CU resident -> 2-4 sequential generations per CU -> gen N+1's staging
// (HBM read) overlaps gen N's compute + epilogue (HBM write). Byte totals
// unchanged; per-wave acc halves to acc[4][1].
__global__ __launch_bounds__(512, 2) void vq_main(const float* __restrict__ lat,
                                                  const float* __restrict__ emb,
                                                  const unsigned char* __restrict__ eprep,
                                                  const float* __restrict__ c0arr,
                                                  float* __restrict__ out,
                                                  float* __restrict__ loss_slot) {
  __shared__ __align__(16) unsigned char xlds[BM * LDS_STRIDE];
  __shared__ unsigned smax[BM];
  __shared__ float lred[8];

  const int tid = threadIdx.x;
  const int lane = tid & 63;
  const int cg = tid >> 6;           // wave 0..7 = code-group (16 codes per ct)
  const int lane15 = lane & 15;
  const int quad = lane >> 4;
  const size_t rowbase_g = (size_t)blockIdx.x * BM;

  // ---- stage X tile: fp32 global -> fp8 LDS; accumulate ||x||^2 in fp32 ----
  if (tid < BM) smax[tid] = 0u;
  float x2 = 0.0f;
  const v4f* latv = (const v4f*)(lat + rowbase_g * DIM);
  #pragma unroll
  for (int i = 0; i < 8; ++i) {
    int g = i * 512 + tid;           // 4096 float4 per tile
    int row = g >> 6;                // 64 float4 per row
    int c4 = g & 63;
    v4f v = latv[g];
    x2 = fmaf(v.x, v.x, x2); x2 = fmaf(v.y, v.y, x2);
    x2 = fmaf(v.z, v.z, x2); x2 = fmaf(v.w, v.w, x2);
    unsigned w = cvt_pk_fp8_lo(v.x, v.y);
    w = cvt_pk_fp8_hi(v.z, v.w, w);
    *(unsigned*)(&xlds[row * LDS_STRIDE + c4 * 4]) = w;
  }

  // hoist per-ct column constants while the staging stores drain
  float c0v[8];
  #pragma unroll
  for (int ct = 0; ct < 8; ++ct)
    c0v[ct] = c0arr[ct * 128 + cg * 16 + lane15];
  __syncthreads();

  // ---- MFMA score tiles + running packed argmax ----
  unsigned kmax[16];
  #pragma unroll
  for (int s = 0; s < 16; ++s) kmax[s] = 0u;

  const long* __restrict__ bptr = (const long*)eprep;

  for (int ct = 0; ct < 8; ++ct) {           // 8 code tiles of 128 (16 per wave)
    const int cb = ct * 128 + cg * 16;       // wave's code base (16 codes)
    const int c16b = cb >> 4;

    v4f acc[4];
    #pragma unroll
    for (int mf = 0; mf < 4; ++mf)
      acc[mf] = (v4f){c0v[ct], c0v[ct], c0v[ct], c0v[ct]};

    #pragma unroll
    for (int kk = 0; kk < 8; ++kk) {         // D=256 in steps of 32
      const long b = bptr[(c16b * 8 + kk) * 64 + lane];
      #pragma unroll
      for (int mf = 0; mf < 4; ++mf) {
        const long a = *(const long*)(&xlds[(mf * 16 + lane15) * LDS_STRIDE + kk * 32 + quad * 8]);
        acc[mf] = __builtin_amdgcn_mfma_f32_16x16x32_fp8_fp8(a, b, acc[mf], 0, 0, 0);
      }
    }

    // pack: key = (acc_bits & ~1023) | (1023-code); larger acc = smaller dist.
    const unsigned cc = (unsigned)(1023 - (cb + lane15));
    #pragma unroll
    for (int mf = 0; mf < 4; ++mf)
      #pragma unroll
      for (int i = 0; i < 4; ++i) {
        const unsigned key =
            (__builtin_bit_cast(unsigned, acc[mf][i]) & 0xFFFFFC00u) | cc;
        const int s = mf * 4 + i;
        kmax[s] = key > kmax[s] ? key : kmax[s];
      }
  }

  // ---- reduce across the 16 lanes sharing a quad (single u32 max) ----
  #pragma unroll
  for (int s = 0; s < 16; ++s) {
    #pragma unroll
    for (int mask = 1; mask <= 8; mask <<= 1) {
      const unsigned o = __shfl_xor(kmax[s], mask);
      kmax[s] = o > kmax[s] ? o : kmax[s];
    }
  }
  // cross-wave combine: 4 lanes/wave x 16 rows each via LDS atomicMax (8 waves)
  if (lane15 == 0) {
    #pragma unroll
    for (int mf = 0; mf < 4; ++mf)
      #pragma unroll
      for (int i = 0; i < 4; ++i)
        atomicMax(&smax[mf * 16 + quad * 4 + i], kmax[mf * 4 + i]);
  }
  __syncthreads();

  // ---- epilogue: gather + store only. wave cg owns rows cg*8..cg*8+7 ----
  float* outg = out + rowbase_g * DIM;
  #pragma unroll
  for (int j = 0; j < 8; ++j) {
    const int r = cg * 8 + j;
    const int code = (int)((~smax[r]) & 1023u);
    const v4f ev = *(const v4f*)(emb + code * DIM + lane * 4);
    *(v4f*)(outg + (size_t)r * DIM + lane * 4) = ev;
  }

  // ---- loss: dist_row = ||x||^2 - 2*(acc_win-256)/512; one atomic per block ----
  #pragma unroll
  for (int off = 32; off; off >>= 1) x2 += __shfl_down(x2, off);
  if (lane == 0) lred[cg] = x2;
  float ssum = 0.0f;
  if (cg == 0) {            // wave 0: decode the 64 winners' scaled scores
    ssum = __builtin_bit_cast(float, smax[lane] & 0xFFFFFC00u) - 256.0f;
    #pragma unroll
    for (int off = 32; off; off >>= 1) ssum += __shfl_down(ssum, off);
  }
  __syncthreads();
  if (tid == 0) {
    float xs = 0.0f;
    #pragma unroll
    for (int c = 0; c < 8; ++c) xs += lred[c];
    atomicAdd(loss_slot, (xs - ssum * (2.0f / 512.0f)) * (1.25f / 16777216.0f));
  }
}

extern "C" void kernel_launch(void* const* d_in, const int* in_sizes, int n_in,
                              void* d_out, int out_size, void* d_ws, size_t ws_size,
                              hipStream_t stream) {
  const float* lat = (const float*)d_in[0];   // [8192, 2048] fp32
  const float* emb = (const float*)d_in[1];   // [1024, 256] fp32
  float* out = (float*)d_out;                 // [16777216] quantized_st + [1] vq_loss
  unsigned char* eprep = (unsigned char*)d_ws;                      // 256 KiB
  float* c0 = (float*)((char*)d_ws + NUM_CODES * DIM);
  float* loss_slot = out + (size_t)OUT0_ELEMS;

  vq_prep<<<NUM_CODES, 256, 0, stream>>>(emb, eprep, c0, loss_slot);
  vq_main<<<NROWS / BM, 512, 0, stream>>>(lat, emb, eprep, c0, out, loss_slot);
}

// Round 8
// 131.683 us; speedup vs baseline: 1.4476x; 1.0384x over previous
//
#include <hip/hip_runtime.h>
#include <cstdint>
#include <cstddef>

// Problem constants
#define NUM_CODES 1024
#define DIM       256
#define NROWS     65536          // BATCH(8192) * NODE(8)
#define BM        64             // rows per block
#define LDS_STRIDE 272           // 256 fp8 bytes + 16 pad (16B-aligned rows)
#define OUT0_ELEMS 16777216      // 8192*8*256

typedef float v4f  __attribute__((ext_vector_type(4)));
typedef int   v4i  __attribute__((ext_vector_type(4)));
typedef int   v8i  __attribute__((ext_vector_type(8)));

// v_cvt_pk_fp8_f32: word-select (4th arg) must be a compile-time constant.
__device__ inline unsigned cvt_pk_fp8_lo(float lo, float hi) {
  return (unsigned)__builtin_amdgcn_cvt_pk_fp8_f32(lo, hi, 0, false);
}
__device__ inline unsigned cvt_pk_fp8_hi(float lo, float hi, unsigned old) {
  return (unsigned)__builtin_amdgcn_cvt_pk_fp8_f32(lo, hi, (int)old, true);
}

// load 32 bytes (16B-aligned) as the v8i MFMA operand
__device__ inline v8i ld32(const void* p) {
  v4i lo = *(const v4i*)p;
  v4i hi = *(const v4i*)((const char*)p + 16);
  return (v8i){lo.x, lo.y, lo.z, lo.w, hi.x, hi.y, hi.z, hi.w};
}

// One block per code k (1024 blocks, 256 threads = one per d).
// B stored as e4m3 of (512*e): raw e in (-1e-3,1e-3) is DENORMAL in e4m3 --
// scaling by 512 puts it in the normal range.
// c0[k] = 256 - 256*||e||^2 : MFMA C-init, so after the K-loop
// acc = 256 + 512*(dot - ||e||^2/2) in [82, 430] > 0 (Cauchy-Schwarz worst case)
// => u32 compare == f32 compare for the packed argmax key.
// R8: eprep in the K=128 MX fragment layout for mfma_scale_f32_16x16x128_f8f6f4:
// lane l holds B[k=(l>>4)*32+j][col=l&15], j=0..31; tile = (c16, kk2) of 2048B.
__global__ __launch_bounds__(256) void vq_prep(const float* __restrict__ emb,
                                               unsigned char* __restrict__ eprep,
                                               float* __restrict__ c0,
                                               float* __restrict__ loss_slot) {
  const int k = blockIdx.x;
  const int d = threadIdx.x;
  float v = emb[k * DIM + d];

  float sq = v * v;
  #pragma unroll
  for (int off = 32; off; off >>= 1) sq += __shfl_down(sq, off);
  __shared__ float red[4];
  const int lane = threadIdx.x & 63, wv = threadIdx.x >> 6;
  if (lane == 0) red[wv] = sq;
  __syncthreads();
  if (threadIdx.x == 0) c0[k] = 256.0f - 256.0f * (red[0] + red[1] + red[2] + red[3]);
  if (blockIdx.x == 0 && threadIdx.x == 0) *loss_slot = 0.0f;

  const int c16 = k >> 4;
  const int kk2 = d >> 7;          // which K=128 slice (0..1)
  const int q   = (d >> 5) & 3;    // 32-block within the slice
  const int j   = d & 31;
  const int l   = q * 16 + (k & 15);
  const unsigned b8 = cvt_pk_fp8_lo(512.0f * v, 512.0f * v) & 0xFFu;
  eprep[(((c16 * 2 + kk2) * 64) + l) * 32 + j] = (unsigned char)b8;
}

// 1024 blocks x 512 threads (8 waves, each owns 16 codes per ct).
// R1/R2 law: no launch-bounds demand below the working set -> (512,2).
// R3: plain out-stores. R6: don't pin loops / hand-roll CSE. R7: 8-wave
// oversubscription overlaps generations (48.2us).
// R8: MX-scaled fp8 MFMA (16x16x128, scales=1.0=0x7F e8m0) -- bit-equivalent
// fp8 math at ~4.66 PF vs the ~2.1 PF non-scaled rate. MFMA pipe 16.4->7.4us;
// hot loop has 4x fewer MFMA + B-load instructions. Same bytes everywhere.
__global__ __launch_bounds__(512, 2) void vq_main(const float* __restrict__ lat,
                                                  const float* __restrict__ emb,
                                                  const unsigned char* __restrict__ eprep,
                                                  const float* __restrict__ c0arr,
                                                  float* __restrict__ out,
                                                  float* __restrict__ loss_slot) {
  __shared__ __align__(16) unsigned char xlds[BM * LDS_STRIDE];
  __shared__ unsigned smax[BM];
  __shared__ float lred[8];

  const int tid = threadIdx.x;
  const int lane = tid & 63;
  const int cg = tid >> 6;           // wave 0..7 = code-group (16 codes per ct)
  const int lane15 = lane & 15;
  const int q4 = lane >> 4;          // 32-block index within K=128
  const size_t rowbase_g = (size_t)blockIdx.x * BM;

  // ---- stage X tile: fp32 global -> fp8 LDS; accumulate ||x||^2 in fp32 ----
  if (tid < BM) smax[tid] = 0u;
  float x2 = 0.0f;
  const v4f* latv = (const v4f*)(lat + rowbase_g * DIM);
  #pragma unroll
  for (int i = 0; i < 8; ++i) {
    int g = i * 512 + tid;           // 4096 float4 per tile
    int row = g >> 6;                // 64 float4 per row
    int c4 = g & 63;
    v4f v = latv[g];
    x2 = fmaf(v.x, v.x, x2); x2 = fmaf(v.y, v.y, x2);
    x2 = fmaf(v.z, v.z, x2); x2 = fmaf(v.w, v.w, x2);
    unsigned w = cvt_pk_fp8_lo(v.x, v.y);
    w = cvt_pk_fp8_hi(v.z, v.w, w);
    *(unsigned*)(&xlds[row * LDS_STRIDE + c4 * 4]) = w;
  }

  // hoist per-ct column constants while the staging stores drain
  float c0v[8];
  #pragma unroll
  for (int ct = 0; ct < 8; ++ct)
    c0v[ct] = c0arr[ct * 128 + cg * 16 + lane15];
  __syncthreads();

  // ---- MFMA score tiles + running packed argmax ----
  unsigned kmax[16];
  #pragma unroll
  for (int s = 0; s < 16; ++s) kmax[s] = 0u;

  for (int ct = 0; ct < 8; ++ct) {           // 8 code tiles of 128 (16 per wave)
    const int cb = ct * 128 + cg * 16;       // wave's code base (16 codes)
    const int c16b = cb >> 4;

    v4f acc[4];
    #pragma unroll
    for (int mf = 0; mf < 4; ++mf)
      acc[mf] = (v4f){c0v[ct], c0v[ct], c0v[ct], c0v[ct]};

    v8i b[2];
    #pragma unroll
    for (int kk2 = 0; kk2 < 2; ++kk2)
      b[kk2] = ld32(eprep + (((size_t)(c16b * 2 + kk2) * 64) + lane) * 32);

    #pragma unroll
    for (int kk2 = 0; kk2 < 2; ++kk2)
      #pragma unroll
      for (int mf = 0; mf < 4; ++mf) {
        const v8i a = ld32(&xlds[(mf * 16 + lane15) * LDS_STRIDE + kk2 * 128 + q4 * 32]);
        acc[mf] = __builtin_amdgcn_mfma_scale_f32_16x16x128_f8f6f4(
            a, b[kk2], acc[mf], 0, 0,                 // cbsz=0 (e4m3), blgp=0 (e4m3)
            0, 0x7F7F7F7F, 0, 0x7F7F7F7F);            // scales = 1.0 (e8m0 127)
      }

    // pack: key = (acc_bits & ~1023) | (1023-code); larger acc = smaller dist.
    const unsigned cc = (unsigned)(1023 - (cb + lane15));
    #pragma unroll
    for (int mf = 0; mf < 4; ++mf)
      #pragma unroll
      for (int i = 0; i < 4; ++i) {
        const unsigned key =
            (__builtin_bit_cast(unsigned, acc[mf][i]) & 0xFFFFFC00u) | cc;
        const int s = mf * 4 + i;
        kmax[s] = key > kmax[s] ? key : kmax[s];
      }
  }

  // ---- reduce across the 16 lanes sharing a quad (single u32 max) ----
  #pragma unroll
  for (int s = 0; s < 16; ++s) {
    #pragma unroll
    for (int mask = 1; mask <= 8; mask <<= 1) {
      const unsigned o = __shfl_xor(kmax[s], mask);
      kmax[s] = o > kmax[s] ? o : kmax[s];
    }
  }
  // cross-wave combine: 4 lanes/wave x 16 rows each via LDS atomicMax (8 waves)
  if (lane15 == 0) {
    #pragma unroll
    for (int mf = 0; mf < 4; ++mf)
      #pragma unroll
      for (int i = 0; i < 4; ++i)
        atomicMax(&smax[mf * 16 + q4 * 4 + i], kmax[mf * 4 + i]);
  }
  __syncthreads();

  // ---- epilogue: gather + store only. wave cg owns rows cg*8..cg*8+7 ----
  float* outg = out + rowbase_g * DIM;
  #pragma unroll
  for (int j = 0; j < 8; ++j) {
    const int r = cg * 8 + j;
    const int code = (int)((~smax[r]) & 1023u);
    const v4f ev = *(const v4f*)(emb + code * DIM + lane * 4);
    *(v4f*)(outg + (size_t)r * DIM + lane * 4) = ev;
  }

  // ---- loss: dist_row = ||x||^2 - 2*(acc_win-256)/512; one atomic per block ----
  #pragma unroll
  for (int off = 32; off; off >>= 1) x2 += __shfl_down(x2, off);
  if (lane == 0) lred[cg] = x2;
  float ssum = 0.0f;
  if (cg == 0) {            // wave 0: decode the 64 winners' scaled scores
    ssum = __builtin_bit_cast(float, smax[lane] & 0xFFFFFC00u) - 256.0f;
    #pragma unroll
    for (int off = 32; off; off >>= 1) ssum += __shfl_down(ssum, off);
  }
  __syncthreads();
  if (tid == 0) {
    float xs = 0.0f;
    #pragma unroll
    for (int c = 0; c < 8; ++c) xs += lred[c];
    atomicAdd(loss_slot, (xs - ssum * (2.0f / 512.0f)) * (1.25f / 16777216.0f));
  }
}

extern "C" void kernel_launch(void* const* d_in, const int* in_sizes, int n_in,
                              void* d_out, int out_size, void* d_ws, size_t ws_size,
                              hipStream_t stream) {
  const float* lat = (const float*)d_in[0];   // [8192, 2048] fp32
  const float* emb = (const float*)d_in[1];   // [1024, 256] fp32
  float* out = (float*)d_out;                 // [16777216] quantized_st + [1] vq_loss
  unsigned char* eprep = (unsigned char*)d_ws;                      // 256 KiB
  float* c0 = (float*)((char*)d_ws + NUM_CODES * DIM);
  float* loss_slot = out + (size_t)OUT0_ELEMS;

  vq_prep<<<NUM_CODES, 256, 0, stream>>>(emb, eprep, c0, loss_slot);
  vq_main<<<NROWS / BM, 512, 0, stream>>>(lat, emb, eprep, c0, out, loss_slot);
}